// Round 16
// baseline (790.686 us; speedup 1.0000x reference)
//
#include <hip/hip_runtime.h>
#include <hip/hip_bf16.h>
#include <utility>

// MultiHeadAttention: x (8,16,2048,128) fp32, Q=K=V=x per (b,s) head.
// R16: R15 skeleton + zero-VALU steady-state addressing: all 16 swizzled LDS
// read addresses precomputed once; buffer index compile-time (unroll-by-3) so
// the buffer offset folds into ds_read offset:N. Counted vmcnt(4) retained.

#define NSEQ   2048
#define DIM    128
#define KVBLK  32
#define TILES  (NSEQ / KVBLK)       // 64
#define IMG    (KVBLK * DIM)        // 4096 shorts = 8 KB per image
// EC = (1/512) * log2(e): exp(s/512) == exp2(s*EC); folded into Q.
#define EC (1.44269504088896f / 512.0f)

typedef short s8v __attribute__((ext_vector_type(8)));
typedef float f4   __attribute__((ext_vector_type(4)));
typedef float f16v __attribute__((ext_vector_type(16)));
typedef unsigned int u2 __attribute__((ext_vector_type(2)));
typedef unsigned int u4 __attribute__((ext_vector_type(4)));

typedef __attribute__((address_space(1))) const void glob_t;
typedef __attribute__((address_space(3))) void lds_t;

__device__ __forceinline__ unsigned pk2(float a, float b) {
    union { __hip_bfloat162 h; unsigned u; } c;
    c.h = __float22bfloat162_rn(make_float2(a, b));
    return c.u;
}
__device__ __forceinline__ int swz32k(int r) { return ((r & 7) ^ ((r >> 3) & 3)) << 3; }
__device__ __forceinline__ int swz(int r)    { return ((r & 7) ^ ((r >> 3) & 7)) << 3; }

// ---------------- pre-pass: x -> bf16 swizzled 32-row images in ws ----------------
__global__ __launch_bounds__(256)
void prepass(const float* __restrict__ x, short* __restrict__ wsK,
             short* __restrict__ wsV) {
    const int b = blockIdx.x;                   // 4096 blocks, 64 rows = 2 tiles
    const float* src = x + (size_t)b * (64 * DIM);
    short* dK = wsK + (size_t)b * 2 * IMG;
    short* dV = wsV + (size_t)b * 2 * IMG;
    const int rw = threadIdx.x >> 4;
    const int cg = threadIdx.x & 15;
    const int tile = rw >> 3;
    const int ul   = 4 * (rw & 7);

    f4 ld[8];
    const float* s = src + (size_t)(4 * rw) * DIM + 8 * cg;
#pragma unroll
    for (int i = 0; i < 4; ++i) {
        ld[2*i]   = *(const f4*)(s + i * DIM);
        ld[2*i+1] = *(const f4*)(s + i * DIM + 4);
    }
#pragma unroll
    for (int i = 0; i < 4; ++i) {               // K image rows (16B stores)
        const int rl = ul + i;
        u4 kv = { pk2(ld[2*i][0],   ld[2*i][1]),   pk2(ld[2*i][2],   ld[2*i][3]),
                  pk2(ld[2*i+1][0], ld[2*i+1][1]), pk2(ld[2*i+1][2], ld[2*i+1][3]) };
        *(u4*)&dK[tile * IMG + ((rl * DIM + 8 * cg) ^ swz32k(rl))] = kv;
    }
#pragma unroll
    for (int j = 0; j < 8; ++j) {               // Vt image rows (8B stores)
        const int d  = 8 * cg + j;
        const int hi = j >> 2, jj = j & 3;
        u2 vv = { pk2(ld[0 + hi][jj], ld[2 + hi][jj]),
                  pk2(ld[4 + hi][jj], ld[6 + hi][jj]) };
        *(u2*)&dV[tile * IMG + ((d * KVBLK + ul) ^ swz32k(d))] = vv;
    }
}

// ---------------- main kernel: precomputed-address 3-buffer pipeline ----------------
__global__ __launch_bounds__(256, 3)
void attn_pa(const float* __restrict__ x, const short* __restrict__ wsK,
             const short* __restrict__ wsV, float* __restrict__ out) {
    const int bid  = blockIdx.x;                    // 2048 blocks
    const int wg   = (bid & 7) * 256 + (bid >> 3);  // XCD swizzle (2048 % 8 == 0)
    const int head = wg >> 4;
    const int qb   = wg & 15;

    float* __restrict__ oh = out + (size_t)head * (NSEQ * DIM);
    const short* gK = wsK + (size_t)head * TILES * IMG;
    const short* gV = wsV + (size_t)head * TILES * IMG;

    const int tid  = threadIdx.x;
    const int lane = tid & 63;
    const int wave = tid >> 6;
    const int l31  = lane & 31;
    const int h    = lane >> 5;

    __shared__ __align__(16) short sK [3][IMG];   // 24 KB
    __shared__ __align__(16) short sVt[3][IMG];   // 24 KB

    // ---- Q frags (x * EC, bf16) ----
    const int qw0 = qb * 128 + wave * 32;
    s8v Qf[8];
    {
        const float* qp = x + (size_t)head * (NSEQ * DIM)
                            + (size_t)(qw0 + l31) * DIM + 8 * h;
#pragma unroll
        for (int ks = 0; ks < 8; ++ks) {
            f4 a = *(const f4*)(qp + ks * 16);
            f4 b = *(const f4*)(qp + ks * 16 + 4);
            u4 q = { pk2(a[0] * EC, a[1] * EC), pk2(a[2] * EC, a[3] * EC),
                     pk2(b[0] * EC, b[1] * EC), pk2(b[2] * EC, b[3] * EC) };
            Qf[ks] = *(s8v*)&q;
        }
    }

    f16v accO[4];
#pragma unroll
    for (int dt = 0; dt < 4; ++dt) accO[dt] = (f16v)(0.f);
    float lsum = 0.f;

    // ---- precomputed swizzled LDS read addresses (buffer 0; statically indexed) ----
    const int kbase = l31 * DIM + 8 * h;
    const int ksz   = swz32k(l31);
    const short* kaddr[8];
#pragma unroll
    for (int ks = 0; ks < 8; ++ks)
        kaddr[ks] = &sK[0][(kbase + ks * 16) ^ ksz];
    const short* vaddr[8];
#pragma unroll
    for (int dt = 0; dt < 4; ++dt) {
        const int d  = dt * 32 + l31;
        const int vb = d * KVBLK + 8 * h;
        const int vs = swz32k(d);
        vaddr[2 * dt]     = &sVt[0][(vb) ^ vs];
        vaddr[2 * dt + 1] = &sVt[0][(vb + 16) ^ vs];
    }

    // staging: 4 loads per body (K x2 then V x2); fixed order for vmcnt math
    const int soff = wave * 1024 + lane * 8;
    auto stage = [&](int b, int t) {
        const short* srcK = gK + (size_t)t * IMG + soff;
        const short* srcV = gV + (size_t)t * IMG + soff;
#pragma unroll
        for (int i = 0; i < 2; ++i)
            __builtin_amdgcn_global_load_lds((glob_t*)(srcK + i * 512),
                (lds_t*)&sK[b][soff + i * 512], 16, 0, 0);
#pragma unroll
        for (int i = 0; i < 2; ++i)
            __builtin_amdgcn_global_load_lds((glob_t*)(srcV + i * 512),
                (lds_t*)&sVt[b][soff + i * 512], 16, 0, 0);
    };

    // per-tile compute, buffer B compile-time: LDS reads = precomputed addr + offset:N
    auto compute = [&](auto Bc) {
        constexpr int B    = decltype(Bc)::value;
        constexpr int BOFF = B * (IMG * 2);   // byte offset of buffer B
        f16v accS = (f16v)(0.f);
        __builtin_amdgcn_s_setprio(1);
#pragma unroll
        for (int ks = 0; ks < 8; ++ks) {
            s8v Kf = *(const s8v*)((const char*)kaddr[ks] + BOFF);
            accS = __builtin_amdgcn_mfma_f32_32x32x16_bf16(Kf, Qf[ks], accS, 0, 0, 0);
        }
        __builtin_amdgcn_s_setprio(0);

        f16v p;
        float part = 0.f;
#pragma unroll
        for (int r = 0; r < 16; ++r) {
            float v = __builtin_amdgcn_exp2f(accS[r]);
            p[r] = v; part += v;
        }
        lsum += part;

        s8v Pf0, Pf1;
        {
            unsigned x0 = pk2(p[0], p[1]), x1 = pk2(p[2], p[3]);
            unsigned y0 = pk2(p[4], p[5]), y1 = pk2(p[6], p[7]);
            auto t0 = __builtin_amdgcn_permlane32_swap(x0, y0, false, false);
            auto t1 = __builtin_amdgcn_permlane32_swap(x1, y1, false, false);
            u4 w = { (unsigned)t0[0], (unsigned)t1[0], (unsigned)t0[1], (unsigned)t1[1] };
            Pf0 = *(s8v*)&w;
        }
        {
            unsigned x0 = pk2(p[8], p[9]),  x1 = pk2(p[10], p[11]);
            unsigned y0 = pk2(p[12], p[13]), y1 = pk2(p[14], p[15]);
            auto t0 = __builtin_amdgcn_permlane32_swap(x0, y0, false, false);
            auto t1 = __builtin_amdgcn_permlane32_swap(x1, y1, false, false);
            u4 w = { (unsigned)t0[0], (unsigned)t1[0], (unsigned)t0[1], (unsigned)t1[1] };
            Pf1 = *(s8v*)&w;
        }

        __builtin_amdgcn_s_setprio(1);
#pragma unroll
        for (int dt = 0; dt < 4; ++dt) {
            s8v Vf0 = *(const s8v*)((const char*)vaddr[2 * dt]     + BOFF);
            s8v Vf1 = *(const s8v*)((const char*)vaddr[2 * dt + 1] + BOFF);
            accO[dt] = __builtin_amdgcn_mfma_f32_32x32x16_bf16(Pf0, Vf0, accO[dt], 0, 0, 0);
            accO[dt] = __builtin_amdgcn_mfma_f32_32x32x16_bf16(Pf1, Vf1, accO[dt], 0, 0, 0);
        }
        __builtin_amdgcn_s_setprio(0);
    };

    // body T (buffer B = T%3 compile-time): stage tile T+2 into buf (B+2)%3,
    // compute tile T, counted vmcnt(4) drains body T-1's loads only.
    auto body = [&](auto Bc, int T) {
        constexpr int B = decltype(Bc)::value;
        stage((B + 2) % 3, T + 2);
        compute(Bc);
        asm volatile("s_waitcnt vmcnt(4)" ::: "memory");
        __builtin_amdgcn_s_barrier();
        __builtin_amdgcn_sched_barrier(0);
    };

    // ---- prologue: tiles 0,1 staged; wait tile-0 (4 newest still pending) ----
    stage(0, 0); stage(1, 1);
    asm volatile("s_waitcnt vmcnt(4)" ::: "memory");
    __builtin_amdgcn_s_barrier();
    __builtin_amdgcn_sched_barrier(0);

    for (int tt = 0; tt < 60; tt += 3) {
        body(std::integral_constant<int, 0>{}, tt);
        body(std::integral_constant<int, 1>{}, tt + 1);
        body(std::integral_constant<int, 2>{}, tt + 2);
    }
    body(std::integral_constant<int, 0>{}, 60);
    body(std::integral_constant<int, 1>{}, 61);

    // body 62: compute buf 2 (tile 62); then full drain for tile 63 (staged @61)
    compute(std::integral_constant<int, 2>{});
    asm volatile("s_waitcnt vmcnt(0)" ::: "memory");
    __builtin_amdgcn_s_barrier();
    __builtin_amdgcn_sched_barrier(0);

    // body 63: last tile in buf 0
    compute(std::integral_constant<int, 0>{});

    // ---- epilogue ----
    const float tot = lsum + __shfl_xor(lsum, 32);
    const float inv = 1.f / tot;
#pragma unroll
    for (int r = 0; r < 16; ++r) {
        const int q      = (r & 3) + 8 * (r >> 2) + 4 * h;
        const float invq = __shfl(inv, q, 32);
        float* op = oh + (size_t)(qw0 + q) * DIM + l31;
#pragma unroll
        for (int dt = 0; dt < 4; ++dt)
            op[dt * 32] = accO[dt][r] * invq;
    }
}

// ---------------- fallback (ws too small): proven no-ws kernel ----------------
__global__ __launch_bounds__(256, 2)
void attn_fwd_fb(const float* __restrict__ x, float* __restrict__ out) {
    const int bid  = blockIdx.x;
    const int wg   = (bid & 7) * 256 + (bid >> 3);
    const int head = wg >> 4;
    const int qb   = wg & 15;
    const float* __restrict__ xh = x   + (size_t)head * (NSEQ * DIM);
    float* __restrict__       oh = out + (size_t)head * (NSEQ * DIM);
    const int tid  = threadIdx.x;
    const int lane = tid & 63;
    const int wave = tid >> 6;
    const int l31  = lane & 31;
    const int h    = lane >> 5;
    __shared__ __align__(16) short sK [64 * DIM];
    __shared__ __align__(16) short sVt[DIM * 64];
    const int qw0 = qb * 128 + wave * 32;
    s8v Qf[8];
    {
        const float* qp = xh + (size_t)(qw0 + l31) * DIM + 8 * h;
#pragma unroll
        for (int ks = 0; ks < 8; ++ks) {
            f4 a = *(const f4*)(qp + ks * 16);
            f4 b = *(const f4*)(qp + ks * 16 + 4);
            u4 q = { pk2(a[0] * EC, a[1] * EC), pk2(a[2] * EC, a[3] * EC),
                     pk2(b[0] * EC, b[1] * EC), pk2(b[2] * EC, b[3] * EC) };
            Qf[ks] = *(s8v*)&q;
        }
    }
    f16v accO[4];
#pragma unroll
    for (int dt = 0; dt < 4; ++dt) accO[dt] = (f16v)(0.f);
    float lsum = 0.f;
    const int rw = tid >> 4;
    const int cg = tid & 15;
    f4 ld[8];
    {
        const float* s = xh + (size_t)(4 * rw) * DIM + 8 * cg;
#pragma unroll
        for (int i = 0; i < 4; ++i) {
            ld[2*i]   = *(const f4*)(s + i * DIM);
            ld[2*i+1] = *(const f4*)(s + i * DIM + 4);
        }
    }
    for (int kv0 = 0; kv0 < NSEQ; kv0 += 64) {
#pragma unroll
        for (int i = 0; i < 4; ++i) {
            const int r = 4 * rw + i;
            u4 kv = { pk2(ld[2*i][0],   ld[2*i][1]),   pk2(ld[2*i][2],   ld[2*i][3]),
                      pk2(ld[2*i+1][0], ld[2*i+1][1]), pk2(ld[2*i+1][2], ld[2*i+1][3]) };
            *(u4*)&sK[(r * DIM + 8 * cg) ^ swz(r)] = kv;
        }
#pragma unroll
        for (int j = 0; j < 8; ++j) {
            const int d  = 8 * cg + j;
            const int hi = j >> 2, jj = j & 3;
            u2 vv = { pk2(ld[0 + hi][jj], ld[2 + hi][jj]),
                      pk2(ld[4 + hi][jj], ld[6 + hi][jj]) };
            *(u2*)&sVt[(d * 64 + 4 * rw) ^ swz(d)] = vv;
        }
        __syncthreads();
        f16v accS[2];
        accS[0] = (f16v)(0.f); accS[1] = (f16v)(0.f);
        __builtin_amdgcn_s_setprio(1);
#pragma unroll
        for (int ut = 0; ut < 2; ++ut) {
            const int r    = ut * 32 + l31;
            const int base = r * DIM + 8 * h;
            const int sz   = swz(r);
#pragma unroll
            for (int ks = 0; ks < 8; ++ks) {
                s8v Kf = *(const s8v*)&sK[(base + ks * 16) ^ sz];
                accS[ut] = __builtin_amdgcn_mfma_f32_32x32x16_bf16(
                    Kf, Qf[ks], accS[ut], 0, 0, 0);
            }
        }
        __builtin_amdgcn_s_setprio(0);
        if (kv0 + 64 < NSEQ) {
            const float* s = xh + (size_t)(kv0 + 64 + 4 * rw) * DIM + 8 * cg;
#pragma unroll
            for (int i = 0; i < 4; ++i) {
                ld[2*i]   = *(const f4*)(s + i * DIM);
                ld[2*i+1] = *(const f4*)(s + i * DIM + 4);
            }
        }
        float part = 0.f;
#pragma unroll
        for (int ut = 0; ut < 2; ++ut)
#pragma unroll
            for (int r = 0; r < 16; ++r) {
                float v = __builtin_amdgcn_exp2f(accS[ut][r]);
                accS[ut][r] = v;
                part += v;
            }
        lsum += part;
        s8v Pf[4];
#pragma unroll
        for (int ks = 0; ks < 4; ++ks) {
#define PP(f) accS[(f) >> 4][(f) & 15]
            unsigned pa0 = pk2(PP(8*ks + 0), PP(8*ks + 1));
            unsigned pa1 = pk2(PP(8*ks + 2), PP(8*ks + 3));
            unsigned pb0 = pk2(PP(8*ks + 4), PP(8*ks + 5));
            unsigned pb1 = pk2(PP(8*ks + 6), PP(8*ks + 7));
#undef PP
            auto t0 = __builtin_amdgcn_permlane32_swap(pa0, pb0, false, false);
            auto t1 = __builtin_amdgcn_permlane32_swap(pa1, pb1, false, false);
            u4 w = { (unsigned)t0[0], (unsigned)t1[0], (unsigned)t0[1], (unsigned)t1[1] };
            Pf[ks] = *(s8v*)&w;
        }
        __builtin_amdgcn_s_setprio(1);
#pragma unroll
        for (int dt = 0; dt < 4; ++dt) {
            const int d    = dt * 32 + l31;
            const int base = d * 64 + 8 * h;
            const int sz   = swz(d);
#pragma unroll
            for (int ks = 0; ks < 4; ++ks) {
                s8v Vf = *(const s8v*)&sVt[(base + ks * 16) ^ sz];
                accO[dt] = __builtin_amdgcn_mfma_f32_32x32x16_bf16(
                    Pf[ks], Vf, accO[dt], 0, 0, 0);
            }
        }
        __builtin_amdgcn_s_setprio(0);
        __syncthreads();
    }
    const float tot = lsum + __shfl_xor(lsum, 32);
    const float inv = 1.f / tot;
#pragma unroll
    for (int r = 0; r < 16; ++r) {
        const int q      = (r & 3) + 8 * (r >> 2) + 4 * h;
        const float invq = __shfl(inv, q, 32);
        float* op = oh + (size_t)(qw0 + q) * DIM + l31;
#pragma unroll
        for (int dt = 0; dt < 4; ++dt)
            op[dt * 32] = accO[dt][r] * invq;
    }
}

extern "C" void kernel_launch(void* const* d_in, const int* in_sizes, int n_in,
                              void* d_out, int out_size, void* d_ws, size_t ws_size,
                              hipStream_t stream) {
    const float* x = (const float*)d_in[0];
    float* out     = (float*)d_out;
    const size_t perImg = (size_t)128 * TILES * IMG;            // shorts
    const size_t need   = 2 * perImg * sizeof(short);           // 128 MiB
    if (ws_size >= need) {
        short* wsK = (short*)d_ws;
        short* wsV = wsK + perImg;
        hipLaunchKernelGGL(prepass, dim3(4096), dim3(256), 0, stream, x, wsK, wsV);
        hipLaunchKernelGGL(attn_pa, dim3(2048), dim3(256), 0, stream, x, wsK, wsV, out);
    } else {
        hipLaunchKernelGGL(attn_fwd_fb, dim3(2048), dim3(256), 0, stream, x, out);
    }
}

// Round 17
// 352.251 us; speedup vs baseline: 2.2447x; 2.2447x over previous
//
#include <hip/hip_runtime.h>
#include <hip/hip_bf16.h>

// MultiHeadAttention: x (8,16,2048,128) fp32, Q=K=V=x per (b,s) head.
// R17 = R6 restored (best of 6 schedule variants, all within 2%):
// pre-pass bf16 swizzled images in ws; main kernel KVBLK=32 double-buffered
// global_load_lds, 3 blocks/CU, 32x32x16 MFMA, max-free softmax fully
// in-register (swapped QK^T + cvt_pk + permlane32_swap).

#define NSEQ   2048
#define DIM    128
#define KVBLK  32
#define TILES  (NSEQ / KVBLK)       // 64
#define IMG    (KVBLK * DIM)        // 4096 shorts = 8 KB per image
// EC = (1/512) * log2(e): exp(s/512) == exp2(s*EC); folded into Q.
#define EC (1.44269504088896f / 512.0f)

typedef short s8v __attribute__((ext_vector_type(8)));
typedef float f4   __attribute__((ext_vector_type(4)));
typedef float f16v __attribute__((ext_vector_type(16)));
typedef unsigned int u2 __attribute__((ext_vector_type(2)));
typedef unsigned int u4 __attribute__((ext_vector_type(4)));

typedef __attribute__((address_space(1))) const void glob_t;
typedef __attribute__((address_space(3))) void lds_t;

__device__ __forceinline__ unsigned pk2(float a, float b) {
    union { __hip_bfloat162 h; unsigned u; } c;
    c.h = __float22bfloat162_rn(make_float2(a, b));
    return c.u;
}
__device__ __forceinline__ int swz32k(int r) { return ((r & 7) ^ ((r >> 3) & 3)) << 3; }
__device__ __forceinline__ int swz(int r)    { return ((r & 7) ^ ((r >> 3) & 7)) << 3; }

// ---------------- pre-pass: x -> bf16 swizzled 32-row images in ws ----------------
__global__ __launch_bounds__(256)
void prepass(const float* __restrict__ x, short* __restrict__ wsK,
             short* __restrict__ wsV) {
    const int b = blockIdx.x;                   // 4096 blocks, 64 rows = 2 tiles
    const float* src = x + (size_t)b * (64 * DIM);
    short* dK = wsK + (size_t)b * 2 * IMG;
    short* dV = wsV + (size_t)b * 2 * IMG;
    const int rw = threadIdx.x >> 4;
    const int cg = threadIdx.x & 15;
    const int tile = rw >> 3;
    const int ul   = 4 * (rw & 7);

    f4 ld[8];
    const float* s = src + (size_t)(4 * rw) * DIM + 8 * cg;
#pragma unroll
    for (int i = 0; i < 4; ++i) {
        ld[2*i]   = *(const f4*)(s + i * DIM);
        ld[2*i+1] = *(const f4*)(s + i * DIM + 4);
    }
#pragma unroll
    for (int i = 0; i < 4; ++i) {               // K image rows (16B stores)
        const int rl = ul + i;
        u4 kv = { pk2(ld[2*i][0],   ld[2*i][1]),   pk2(ld[2*i][2],   ld[2*i][3]),
                  pk2(ld[2*i+1][0], ld[2*i+1][1]), pk2(ld[2*i+1][2], ld[2*i+1][3]) };
        *(u4*)&dK[tile * IMG + ((rl * DIM + 8 * cg) ^ swz32k(rl))] = kv;
    }
#pragma unroll
    for (int j = 0; j < 8; ++j) {               // Vt image rows (8B stores)
        const int d  = 8 * cg + j;
        const int hi = j >> 2, jj = j & 3;
        u2 vv = { pk2(ld[0 + hi][jj], ld[2 + hi][jj]),
                  pk2(ld[4 + hi][jj], ld[6 + hi][jj]) };
        *(u2*)&dV[tile * IMG + ((d * KVBLK + ul) ^ swz32k(d))] = vv;
    }
}

// ---------------- main kernel: 32q/wave, KVBLK=32 dbuf, 3 blocks/CU ----------------
__global__ __launch_bounds__(256, 3)
void attn_k32(const float* __restrict__ x, const short* __restrict__ wsK,
              const short* __restrict__ wsV, float* __restrict__ out) {
    const int bid  = blockIdx.x;                    // 2048 blocks
    const int wg   = (bid & 7) * 256 + (bid >> 3);  // XCD swizzle (2048 % 8 == 0)
    const int head = wg >> 4;
    const int qb   = wg & 15;

    const float* __restrict__ xh = x   + (size_t)head * (NSEQ * DIM);
    float* __restrict__       oh = out + (size_t)head * (NSEQ * DIM);
    const short* gK = wsK + (size_t)head * TILES * IMG;
    const short* gV = wsV + (size_t)head * TILES * IMG;

    const int tid  = threadIdx.x;
    const int lane = tid & 63;
    const int wave = tid >> 6;
    const int l31  = lane & 31;
    const int h    = lane >> 5;

    __shared__ __align__(16) short sK [2][IMG];   // 16 KB
    __shared__ __align__(16) short sVt[2][IMG];   // 16 KB

    // ---- Q frags (x * EC, bf16): B-operand, lane holds Q[qw0+l31][ks*16+8h+j] ----
    const int qw0 = qb * 128 + wave * 32;
    s8v Qf[8];
    {
        const float* qp = xh + (size_t)(qw0 + l31) * DIM + 8 * h;
#pragma unroll
        for (int ks = 0; ks < 8; ++ks) {
            f4 a = *(const f4*)(qp + ks * 16);
            f4 b = *(const f4*)(qp + ks * 16 + 4);
            u4 q = { pk2(a[0] * EC, a[1] * EC), pk2(a[2] * EC, a[3] * EC),
                     pk2(b[0] * EC, b[1] * EC), pk2(b[2] * EC, b[3] * EC) };
            Qf[ks] = *(s8v*)&q;
        }
    }

    f16v accO[4];
#pragma unroll
    for (int dt = 0; dt < 4; ++dt) accO[dt] = (f16v)(0.f);
    float lsum = 0.f;

    // stage one tile (8 KB K + 8 KB V): 2+2 global_load_lds_dwordx4 per thread
    auto stage = [&](int b, int t) {
        const short* srcK = gK + (size_t)t * IMG;
        const short* srcV = gV + (size_t)t * IMG;
        const int off = wave * 1024 + lane * 8;
#pragma unroll
        for (int i = 0; i < 2; ++i) {
            __builtin_amdgcn_global_load_lds((glob_t*)(srcK + off + i * 512),
                (lds_t*)&sK[b][off + i * 512], 16, 0, 0);
            __builtin_amdgcn_global_load_lds((glob_t*)(srcV + off + i * 512),
                (lds_t*)&sVt[b][off + i * 512], 16, 0, 0);
        }
    };

    stage(0, 0);
    __syncthreads();
    int buf = 0;

    for (int t = 0; t < TILES; ++t) {
        if (t + 1 < TILES) stage(buf ^ 1, t + 1);   // DMA into other buffer

        // ---- QK^T (swapped): accS[r] = P-logit[q=l31][u=(r&3)+8*(r>>2)+4h] ----
        f16v accS = (f16v)(0.f);
        {
            const int base = l31 * DIM + 8 * h;
            const int sz   = swz32k(l31);
            __builtin_amdgcn_s_setprio(1);
#pragma unroll
            for (int ks = 0; ks < 8; ++ks) {
                s8v Kf = *(const s8v*)&sK[buf][(base + ks * 16) ^ sz];
                accS = __builtin_amdgcn_mfma_f32_32x32x16_bf16(Kf, Qf[ks], accS, 0, 0, 0);
            }
            __builtin_amdgcn_s_setprio(0);
        }

        // ---- softmax numerator (max-free) ----
        float part = 0.f;
#pragma unroll
        for (int r = 0; r < 16; ++r) {
            float v = __builtin_amdgcn_exp2f(accS[r]);
            accS[r] = v;
            part += v;
        }
        lsum += part;

        // ---- T12: PV A-frags in-register (8 cvt_pk + 4 permlane32_swap) ----
        s8v Pf[2];
#pragma unroll
        for (int ksl = 0; ksl < 2; ++ksl) {
            unsigned pa0 = pk2(accS[8*ksl + 0], accS[8*ksl + 1]);
            unsigned pa1 = pk2(accS[8*ksl + 2], accS[8*ksl + 3]);
            unsigned pb0 = pk2(accS[8*ksl + 4], accS[8*ksl + 5]);
            unsigned pb1 = pk2(accS[8*ksl + 6], accS[8*ksl + 7]);
            auto t0 = __builtin_amdgcn_permlane32_swap(pa0, pb0, false, false);
            auto t1 = __builtin_amdgcn_permlane32_swap(pa1, pb1, false, false);
            u4 w = { (unsigned)t0[0], (unsigned)t1[0], (unsigned)t0[1], (unsigned)t1[1] };
            Pf[ksl] = *(s8v*)&w;
        }

        // ---- PV: accO[dt] += P[q][u] V[u][dt*32+l31] ----
        __builtin_amdgcn_s_setprio(1);
#pragma unroll
        for (int dt = 0; dt < 4; ++dt) {
            const int d    = dt * 32 + l31;
            const int base = d * KVBLK + 8 * h;
            const int sz   = swz32k(d);
#pragma unroll
            for (int ksl = 0; ksl < 2; ++ksl) {
                s8v Vf = *(const s8v*)&sVt[buf][(base + ksl * 16) ^ sz];
                accO[dt] = __builtin_amdgcn_mfma_f32_32x32x16_bf16(
                    Pf[ksl], Vf, accO[dt], 0, 0, 0);
            }
        }
        __builtin_amdgcn_s_setprio(0);

        __syncthreads();   // drains DMA (next tile resident); this tile's reads done
        buf ^= 1;
    }

    // ---- epilogue: cross-half reduce, broadcast 1/sum, store fp32 ----
    const float tot = lsum + __shfl_xor(lsum, 32);
    const float inv = 1.f / tot;
#pragma unroll
    for (int r = 0; r < 16; ++r) {
        const int q      = (r & 3) + 8 * (r >> 2) + 4 * h;
        const float invq = __shfl(inv, q, 32);
        float* op = oh + (size_t)(qw0 + q) * DIM + l31;
#pragma unroll
        for (int dt = 0; dt < 4; ++dt)
            op[dt * 32] = accO[dt][r] * invq;
    }
}

// ---------------- fallback (ws too small): proven no-ws kernel ----------------
__global__ __launch_bounds__(256, 2)
void attn_fwd_fb(const float* __restrict__ x, float* __restrict__ out) {
    const int bid  = blockIdx.x;
    const int wg   = (bid & 7) * 256 + (bid >> 3);
    const int head = wg >> 4;
    const int qb   = wg & 15;
    const float* __restrict__ xh = x   + (size_t)head * (NSEQ * DIM);
    float* __restrict__       oh = out + (size_t)head * (NSEQ * DIM);
    const int tid  = threadIdx.x;
    const int lane = tid & 63;
    const int wave = tid >> 6;
    const int l31  = lane & 31;
    const int h    = lane >> 5;
    __shared__ __align__(16) short sK [64 * DIM];
    __shared__ __align__(16) short sVt[DIM * 64];
    const int qw0 = qb * 128 + wave * 32;
    s8v Qf[8];
    {
        const float* qp = xh + (size_t)(qw0 + l31) * DIM + 8 * h;
#pragma unroll
        for (int ks = 0; ks < 8; ++ks) {
            f4 a = *(const f4*)(qp + ks * 16);
            f4 b = *(const f4*)(qp + ks * 16 + 4);
            u4 q = { pk2(a[0] * EC, a[1] * EC), pk2(a[2] * EC, a[3] * EC),
                     pk2(b[0] * EC, b[1] * EC), pk2(b[2] * EC, b[3] * EC) };
            Qf[ks] = *(s8v*)&q;
        }
    }
    f16v accO[4];
#pragma unroll
    for (int dt = 0; dt < 4; ++dt) accO[dt] = (f16v)(0.f);
    float lsum = 0.f;
    const int rw = tid >> 4;
    const int cg = tid & 15;
    f4 ld[8];
    {
        const float* s = xh + (size_t)(4 * rw) * DIM + 8 * cg;
#pragma unroll
        for (int i = 0; i < 4; ++i) {
            ld[2*i]   = *(const f4*)(s + i * DIM);
            ld[2*i+1] = *(const f4*)(s + i * DIM + 4);
        }
    }
    for (int kv0 = 0; kv0 < NSEQ; kv0 += 64) {
#pragma unroll
        for (int i = 0; i < 4; ++i) {
            const int r = 4 * rw + i;
            u4 kv = { pk2(ld[2*i][0],   ld[2*i][1]),   pk2(ld[2*i][2],   ld[2*i][3]),
                      pk2(ld[2*i+1][0], ld[2*i+1][1]), pk2(ld[2*i+1][2], ld[2*i+1][3]) };
            *(u4*)&sK[(r * DIM + 8 * cg) ^ swz(r)] = kv;
        }
#pragma unroll
        for (int j = 0; j < 8; ++j) {
            const int d  = 8 * cg + j;
            const int hi = j >> 2, jj = j & 3;
            u2 vv = { pk2(ld[0 + hi][jj], ld[2 + hi][jj]),
                      pk2(ld[4 + hi][jj], ld[6 + hi][jj]) };
            *(u2*)&sVt[(d * 64 + 4 * rw) ^ swz(d)] = vv;
        }
        __syncthreads();
        f16v accS[2];
        accS[0] = (f16v)(0.f); accS[1] = (f16v)(0.f);
        __builtin_amdgcn_s_setprio(1);
#pragma unroll
        for (int ut = 0; ut < 2; ++ut) {
            const int r    = ut * 32 + l31;
            const int base = r * DIM + 8 * h;
            const int sz   = swz(r);
#pragma unroll
            for (int ks = 0; ks < 8; ++ks) {
                s8v Kf = *(const s8v*)&sK[(base + ks * 16) ^ sz];
                accS[ut] = __builtin_amdgcn_mfma_f32_32x32x16_bf16(
                    Kf, Qf[ks], accS[ut], 0, 0, 0);
            }
        }
        __builtin_amdgcn_s_setprio(0);
        if (kv0 + 64 < NSEQ) {
            const float* s = xh + (size_t)(kv0 + 64 + 4 * rw) * DIM + 8 * cg;
#pragma unroll
            for (int i = 0; i < 4; ++i) {
                ld[2*i]   = *(const f4*)(s + i * DIM);
                ld[2*i+1] = *(const f4*)(s + i * DIM + 4);
            }
        }
        float part = 0.f;
#pragma unroll
        for (int ut = 0; ut < 2; ++ut)
#pragma unroll
            for (int r = 0; r < 16; ++r) {
                float v = __builtin_amdgcn_exp2f(accS[ut][r]);
                accS[ut][r] = v;
                part += v;
            }
        lsum += part;
        s8v Pf[4];
#pragma unroll
        for (int ks = 0; ks < 4; ++ks) {
#define PP(f) accS[(f) >> 4][(f) & 15]
            unsigned pa0 = pk2(PP(8*ks + 0), PP(8*ks + 1));
            unsigned pa1 = pk2(PP(8*ks + 2), PP(8*ks + 3));
            unsigned pb0 = pk2(PP(8*ks + 4), PP(8*ks + 5));
            unsigned pb1 = pk2(PP(8*ks + 6), PP(8*ks + 7));
#undef PP
            auto t0 = __builtin_amdgcn_permlane32_swap(pa0, pb0, false, false);
            auto t1 = __builtin_amdgcn_permlane32_swap(pa1, pb1, false, false);
            u4 w = { (unsigned)t0[0], (unsigned)t1[0], (unsigned)t0[1], (unsigned)t1[1] };
            Pf[ks] = *(s8v*)&w;
        }
        __builtin_amdgcn_s_setprio(1);
#pragma unroll
        for (int dt = 0; dt < 4; ++dt) {
            const int d    = dt * 32 + l31;
            const int base = d * 64 + 8 * h;
            const int sz   = swz(d);
#pragma unroll
            for (int ks = 0; ks < 4; ++ks) {
                s8v Vf = *(const s8v*)&sVt[(base + ks * 16) ^ sz];
                accO[dt] = __builtin_amdgcn_mfma_f32_32x32x16_bf16(
                    Pf[ks], Vf, accO[dt], 0, 0, 0);
            }
        }
        __builtin_amdgcn_s_setprio(0);
        __syncthreads();
    }
    const float tot = lsum + __shfl_xor(lsum, 32);
    const float inv = 1.f / tot;
#pragma unroll
    for (int r = 0; r < 16; ++r) {
        const int q      = (r & 3) + 8 * (r >> 2) + 4 * h;
        const float invq = __shfl(inv, q, 32);
        float* op = oh + (size_t)(qw0 + q) * DIM + l31;
#pragma unroll
        for (int dt = 0; dt < 4; ++dt)
            op[dt * 32] = accO[dt][r] * invq;
    }
}

extern "C" void kernel_launch(void* const* d_in, const int* in_sizes, int n_in,
                              void* d_out, int out_size, void* d_ws, size_t ws_size,
                              hipStream_t stream) {
    const float* x = (const float*)d_in[0];
    float* out     = (float*)d_out;
    const size_t perImg = (size_t)128 * TILES * IMG;            // shorts
    const size_t need   = 2 * perImg * sizeof(short);           // 128 MiB
    if (ws_size >= need) {
        short* wsK = (short*)d_ws;
        short* wsV = wsK + perImg;
        hipLaunchKernelGGL(prepass, dim3(4096), dim3(256), 0, stream, x, wsK, wsV);
        hipLaunchKernelGGL(attn_k32, dim3(2048), dim3(256), 0, stream, x, wsK, wsV, out);
    } else {
        hipLaunchKernelGGL(attn_fwd_fb, dim3(2048), dim3(256), 0, stream, x, out);
    }
}